// Round 17
// baseline (11172.467 us; speedup 1.0000x reference)
//
#include <hip/hip_runtime.h>
#include <math.h>

typedef unsigned int uint_t;
typedef unsigned short ushort_t;
typedef __bf16 bf16x8 __attribute__((ext_vector_type(8)));
typedef float f32x4 __attribute__((ext_vector_type(4)));

#define BB 512
#define TT 256
#define DD 32
#define LL 64
#define CC 128
#define HH 512
#define HE 256
#define LOG2PI_ 1.8378770664093453f
#define GK 4097
#define GSCALE 32.0f
#define GZMIN (-64.0f)

__device__ __forceinline__ float softplus_f(float x) {
  float ax = fabsf(x);
  return fmaxf(x, 0.0f) + __logf(1.0f + __expf(-ax));
}
__device__ __forceinline__ float sigmoid_f(float x) {
  return 1.0f / (1.0f + __expf(-x));
}
__device__ __forceinline__ float bf2f(ushort_t s) {
  return __uint_as_float(((uint_t)s) << 16);
}
__device__ __forceinline__ float bflo(uint_t u) { return __uint_as_float(u << 16); }
__device__ __forceinline__ float bfhi(uint_t u) { return __uint_as_float(u & 0xffff0000u); }
__device__ __forceinline__ ushort_t f2bf(float f) {
  uint_t u = __float_as_uint(f);
  return (ushort_t)((u + 0x7fffu + ((u >> 16) & 1u)) >> 16);
}
__device__ __forceinline__ __bf16 bfbits(ushort_t v) {
  __bf16 b; *(ushort_t*)&b = v; return b;
}

#define MFMA_B16(a,b,c) __builtin_amdgcn_mfma_f32_16x16x32_bf16(a,b,c,0,0,0)

// async global->LDS, 16B per lane; aux=1 (sc0) kept from r16 (neutral).
__device__ __forceinline__ void gld16(const ushort_t* g, ushort_t* l) {
  __builtin_amdgcn_global_load_lds(
      (const __attribute__((address_space(1))) unsigned int*)(const void*)g,
      (__attribute__((address_space(3))) unsigned int*)(void*)l, 16, 0, 1);
}

// ---------------- prep: pack weights (identical to r16) ---------------------
__global__ void prep_kernel(
    const float* __restrict__ fW1, const float* __restrict__ hW1,
    const float* __restrict__ fW2, const float* __restrict__ hW2,
    const float* __restrict__ fW3, const float* __restrict__ hW3,
    const float* __restrict__ Wx,  const float* __restrict__ Wh,
    const float* __restrict__ encW, const float* __restrict__ projW,
    ushort_t* __restrict__ W1fp, ushort_t* __restrict__ W1hp,
    ushort_t* __restrict__ W2fp, ushort_t* __restrict__ W2hp,
    ushort_t* __restrict__ W3fp, ushort_t* __restrict__ W3hp,
    ushort_t* __restrict__ encWb,
    uint_t* __restrict__ Wgru, ushort_t* __restrict__ Wgn,
    ushort_t* __restrict__ projWp)
{
  int idx = blockIdx.x*256 + threadIdx.x;
  if (idx < 98304) {
    int f = idx >> 9, e = idx & 511;
    int ks = f >> 5, nt = f & 31, l = e >> 3, j = e & 7;
    int k = ks*32 + ((l>>4)<<3) + j, n = nt*16 + (l & 15);
    W1fp[idx] = f2bf(fW1[k*512 + n]);
  } else if (idx < 131072) {
    int r = idx - 98304;
    int f = r >> 9, e = r & 511;
    int ks = f >> 5, nt = f & 31, l = e >> 3, j = e & 7;
    int k = ks*32 + ((l>>4)<<3) + j, n = nt*16 + (l & 15);
    W1hp[r] = f2bf(hW1[k*512 + n]);
  } else if (idx < 393216) {
    int r = idx - 131072;
    int f = r >> 9, e = r & 511;
    int ks = f >> 5, nt = f & 31, l = e >> 3, j = e & 7;
    int k = ks*32 + ((l>>4)<<3) + j, n = nt*16 + (l & 15);
    W2fp[r] = f2bf(fW2[k*512 + n]);
  } else if (idx < 655360) {
    int r = idx - 393216;
    int f = r >> 9, e = r & 511;
    int ks = f >> 5, nt = f & 31, l = e >> 3, j = e & 7;
    int k = ks*32 + ((l>>4)<<3) + j, n = nt*16 + (l & 15);
    W2hp[r] = f2bf(hW2[k*512 + n]);
  } else if (idx < 688128) {
    int r = idx - 655360;
    int f = r >> 9, e = r & 511;
    int ks = f >> 2, nt = f & 3, l = e >> 3, j = e & 7;
    int k = ks*32 + ((l>>4)<<3) + j, n = nt*16 + (l & 15);
    W3fp[r] = f2bf(fW3[k*64 + n]);
  } else if (idx < 720896) {
    int r = idx - 688128;
    int f = r >> 9, e = r & 511;
    int ks = f >> 2, nt = f & 3, l = e >> 3, j = e & 7;
    int k = ks*32 + ((l>>4)<<3) + j, n = nt*16 + (l & 15);
    W3hp[r] = f2bf(hW3[k*64 + n]);
  } else if (idx < 753664) {
    int r = idx - 720896;
    encWb[r] = f2bf(encW[r]);
  } else if (idx < 827648) {
    int r = idx - 753664;
    int k = r >> 8, j = r & 255;
    float wr, wu, wn;
    if (k < 33) { wr = Wx[k*768 + j]; wu = Wx[k*768 + 256 + j]; wn = Wx[k*768 + 512 + j]; }
    else { int kk = k - 33; wr = Wh[kk*768 + j]; wu = Wh[kk*768 + 256 + j]; wn = Wh[kk*768 + 512 + j]; }
    Wgru[r] = (uint_t)f2bf(wr) | ((uint_t)f2bf(wu) << 16);
    Wgn[r]  = f2bf(wn);
  } else if (idx < 829696) {
    int r = idx - 827648;
    int f = r >> 9, e = r & 511;
    int ks = f >> 1, nt = f & 1, l = e >> 3, j = e & 7;
    int k = ks*32 + ((l>>4)<<3) + j, n = nt*16 + (l & 15);
    projWp[r] = f2bf(projW[k*32 + n]);
  }
}

// ---------------- g-function lookup table -----------------------------------
__global__ void lut_kernel(const float* __restrict__ gw1, const float* __restrict__ gb1,
                           const float* __restrict__ gw2, const float* __restrict__ gb2,
                           float* __restrict__ gtab)
{
  int idx = blockIdx.x*256 + threadIdx.x;
  if (idx >= 64*GK) return;
  int l = idx / GK, i = idx - l*GK;
  float z = GZMIN + (float)i*(1.0f/GSCALE);
  float s = 0.f;
  for (int h = 0; h < 512; ++h)
    s += softplus_f(z*gw1[l*512+h] + gb1[l*512+h]) * gw2[l*512+h];
  gtab[idx] = sigmoid_f(s + gb2[l]);
}

// ---------------- SDE pipelines ----------------------------------------------
#define AP_SCAT(row,k) (((k)>>5)*512 + ((row) + ((((k)>>3)&3)<<4))*8 + ((k)&7))

#define O_INP  0         // 6144
#define O_A1   6144      // 16384
#define O_A2   22528     // 16384
#define O_L3F  38912     // 4096
#define O_L3H  43008     // 4096
#define O_STG  47104     // 106496: 8 waves x (12 ring + 1 trash) x 1KB
#define SMEM_SZ 153600

// depth-8 ring (used for short N=8 phase)
template<int KS>
__device__ __forceinline__ void phase4d8(
    const ushort_t* __restrict__ Wb, int nt0,
    const __bf16* __restrict__ A, ushort_t* __restrict__ slot, int lane, f32x4* acc)
{
  constexpr int N = KS*4;
  const size_t lo = (size_t)lane*8;
  #define GA4(f_) (Wb + (((size_t)(((((f_)<N?(f_):N-1))>>2)*32 + nt0 + ((((f_)<N?(f_):N-1))&3)))<<9) + lo)
  #define SL(f_)  (slot + (((f_) < N) ? (((f_)&7)*512) : (8*512)))
  #pragma unroll
  for (int d = 0; d < 8; ++d) gld16(GA4(d), slot + d*512);
  bf16x8 a  = *(const bf16x8*)(A + lo);
  bf16x8 an = a;
  asm volatile("s_waitcnt vmcnt(7)":::"memory");
  bf16x8 p0 = *(const bf16x8*)(slot + 0*512 + lo);
  asm volatile("s_waitcnt vmcnt(6)":::"memory");
  bf16x8 p1 = *(const bf16x8*)(slot + 1*512 + lo);
  bf16x8 p2, p3;
  for (int f0 = 0; f0 < N; f0 += 4) {
    int ks = f0 >> 2;
    asm volatile("s_waitcnt vmcnt(5)":::"memory");
    p2 = *(const bf16x8*)(slot + ((f0+2)&7)*512 + lo);
    asm volatile("s_waitcnt lgkmcnt(2)":::"memory");
    gld16(GA4(f0+8), SL(f0+8));
    acc[0] = MFMA_B16(a, p0, acc[0]);
    asm volatile("s_waitcnt vmcnt(5)":::"memory");
    p3 = *(const bf16x8*)(slot + ((f0+3)&7)*512 + lo);
    asm volatile("s_waitcnt lgkmcnt(2)":::"memory");
    gld16(GA4(f0+9), SL(f0+9));
    acc[1] = MFMA_B16(a, p1, acc[1]);
    asm volatile("s_waitcnt vmcnt(5)":::"memory");
    p0 = *(const bf16x8*)(slot + ((f0+4)&7)*512 + lo);
    if (ks + 1 < KS) an = *(const bf16x8*)(A + ((size_t)(ks+1)<<9) + lo);
    asm volatile("s_waitcnt lgkmcnt(3)":::"memory");
    gld16(GA4(f0+10), SL(f0+10));
    acc[2] = MFMA_B16(a, p2, acc[2]);
    asm volatile("s_waitcnt vmcnt(5)":::"memory");
    p1 = *(const bf16x8*)(slot + ((f0+5)&7)*512 + lo);
    asm volatile("s_waitcnt lgkmcnt(3)":::"memory");
    gld16(GA4(f0+11), SL(f0+11));
    acc[3] = MFMA_B16(a, p3, acc[3]);
    a = an;
  }
  #undef GA4
  #undef SL
}

// depth-12 ring (sequential addresses, no stagger): steady state vmcnt(9),
// ~9.5 KB in flight per wave. Slot group sg cycles 0,4,8; trash slot 12.
template<int KS>
__device__ __forceinline__ void phase4d12(
    const ushort_t* __restrict__ Wb, int nt0,
    const __bf16* __restrict__ A, ushort_t* __restrict__ slot, int lane, f32x4* acc)
{
  constexpr int N = KS*4;   // >= 16
  const size_t lo = (size_t)lane*8;
  #define GAD(f_) (Wb + (((size_t)((((f_)>>2)*32 + nt0 + ((f_)&3))))<<9) + lo)
  #pragma unroll
  for (int d = 0; d < 12; ++d) gld16(GAD(d), slot + d*512);
  bf16x8 a  = *(const bf16x8*)(A + lo);
  bf16x8 an = a;
  asm volatile("s_waitcnt vmcnt(11)":::"memory");
  bf16x8 p0 = *(const bf16x8*)(slot + 0*512 + lo);
  asm volatile("s_waitcnt vmcnt(10)":::"memory");
  bf16x8 p1 = *(const bf16x8*)(slot + 1*512 + lo);
  bf16x8 p2, p3;
  int sg = 0;
  for (int f0 = 0; f0 < N; f0 += 4) {
    int ks = f0 >> 2;
    int sgn = (sg == 8) ? 0 : sg + 4;
    // j0
    asm volatile("s_waitcnt vmcnt(9)":::"memory");
    p2 = *(const bf16x8*)(slot + (sg+2)*512 + lo);
    asm volatile("s_waitcnt lgkmcnt(2)":::"memory");
    if (f0+12 < N) gld16(GAD(f0+12), slot + sg*512);
    else           gld16(GAD(N-1),   slot + 12*512);
    acc[0] = MFMA_B16(a, p0, acc[0]);
    // j1
    asm volatile("s_waitcnt vmcnt(9)":::"memory");
    p3 = *(const bf16x8*)(slot + (sg+3)*512 + lo);
    asm volatile("s_waitcnt lgkmcnt(2)":::"memory");
    if (f0+13 < N) gld16(GAD(f0+13), slot + (sg+1)*512);
    else           gld16(GAD(N-1),   slot + 12*512);
    acc[1] = MFMA_B16(a, p1, acc[1]);
    // j2
    asm volatile("s_waitcnt vmcnt(9)":::"memory");
    p0 = *(const bf16x8*)(slot + sgn*512 + lo);
    if (ks + 1 < KS) an = *(const bf16x8*)(A + ((size_t)(ks+1)<<9) + lo);
    asm volatile("s_waitcnt lgkmcnt(3)":::"memory");
    if (f0+14 < N) gld16(GAD(f0+14), slot + (sg+2)*512);
    else           gld16(GAD(N-1),   slot + 12*512);
    acc[2] = MFMA_B16(a, p2, acc[2]);
    // j3
    asm volatile("s_waitcnt vmcnt(9)":::"memory");
    p1 = *(const bf16x8*)(slot + (sgn+1)*512 + lo);
    asm volatile("s_waitcnt lgkmcnt(3)":::"memory");
    if (f0+15 < N) gld16(GAD(f0+15), slot + (sg+3)*512);
    else           gld16(GAD(N-1),   slot + 12*512);
    acc[3] = MFMA_B16(a, p3, acc[3]);
    a = an;
    sg = sgn;
  }
  #undef GAD
}

template<int KS, int NTS>
__device__ __forceinline__ void phase1(
    const ushort_t* __restrict__ Wb, int nt,
    const __bf16* __restrict__ A, ushort_t* __restrict__ slot, int lane, f32x4& acc)
{
  constexpr int N = KS;
  const size_t lo = (size_t)lane*8;
  #define GA1(f_) (Wb + (((size_t)((((f_)<N?(f_):N-1))*NTS + nt))<<9) + lo)
  #define SL1(f_)  (slot + (((f_) < N) ? (((f_)&7)*512) : (8*512)))
  #define QA(f_)  (*(const bf16x8*)(A + ((size_t)(((f_)<N?(f_):N-1))<<9) + lo))
  #pragma unroll
  for (int d = 0; d < 8; ++d) gld16(GA1(d), slot + d*512);
  bf16x8 q0 = QA(0);
  asm volatile("s_waitcnt vmcnt(7)":::"memory");
  bf16x8 p0 = *(const bf16x8*)(slot + 0*512 + lo);
  bf16x8 q1 = QA(1);
  asm volatile("s_waitcnt vmcnt(6)":::"memory");
  bf16x8 p1 = *(const bf16x8*)(slot + 1*512 + lo);
  bf16x8 p2, p3, q2, q3;
  for (int f0 = 0; f0 < N; f0 += 4) {
    q2 = QA(f0+2);
    asm volatile("s_waitcnt vmcnt(5)":::"memory");
    p2 = *(const bf16x8*)(slot + ((f0+2)&7)*512 + lo);
    asm volatile("s_waitcnt lgkmcnt(4)":::"memory");
    gld16(GA1(f0+8), SL1(f0+8));
    acc = MFMA_B16(q0, p0, acc);
    q3 = QA(f0+3);
    asm volatile("s_waitcnt vmcnt(5)":::"memory");
    p3 = *(const bf16x8*)(slot + ((f0+3)&7)*512 + lo);
    asm volatile("s_waitcnt lgkmcnt(4)":::"memory");
    gld16(GA1(f0+9), SL1(f0+9));
    acc = MFMA_B16(q1, p1, acc);
    q0 = QA(f0+4);
    asm volatile("s_waitcnt vmcnt(5)":::"memory");
    p0 = *(const bf16x8*)(slot + ((f0+4)&7)*512 + lo);
    asm volatile("s_waitcnt lgkmcnt(4)":::"memory");
    gld16(GA1(f0+10), SL1(f0+10));
    acc = MFMA_B16(q2, p2, acc);
    q1 = QA(f0+5);
    asm volatile("s_waitcnt vmcnt(5)":::"memory");
    p1 = *(const bf16x8*)(slot + ((f0+5)&7)*512 + lo);
    asm volatile("s_waitcnt lgkmcnt(4)":::"memory");
    gld16(GA1(f0+11), SL1(f0+11));
    acc = MFMA_B16(q3, p3, acc);
  }
  #undef GA1
  #undef SL1
  #undef QA
}

// ---------------- mega kernel: 32 SDE blocks + 128 GRU blocks ---------------
__global__ __launch_bounds__(512) void mega_kernel(
  const float* __restrict__ xs, const float* __restrict__ ts,
  const float* __restrict__ eps0, const float* __restrict__ dW,
  const float* __restrict__ qzW, const float* __restrict__ qzb,
  const float* __restrict__ pm, const float* __restrict__ pls,
  const ushort_t* __restrict__ W1fp, const ushort_t* __restrict__ W1hp,
  const ushort_t* __restrict__ W2fp, const ushort_t* __restrict__ W2hp,
  const ushort_t* __restrict__ W3fp, const ushort_t* __restrict__ W3hp,
  const float* __restrict__ fb1, const float* __restrict__ hb1,
  const float* __restrict__ fb2, const float* __restrict__ hb2,
  const float* __restrict__ fb3, const float* __restrict__ hb3,
  const float* __restrict__ gtab,
  const float* __restrict__ gw1, const float* __restrict__ gb1,
  const float* __restrict__ gw2, const float* __restrict__ gb2,
  const uint_t* __restrict__ Wgru, const ushort_t* __restrict__ Wgn,
  const float* __restrict__ grub,
  const ushort_t* __restrict__ encWb, const float* __restrict__ encb,
  const ushort_t* __restrict__ projWp, const float* __restrict__ projb,
  ushort_t* __restrict__ ctxb, uint_t* __restrict__ prog,
  float* __restrict__ out)
{
  __shared__ __align__(16) unsigned char smem[SMEM_SZ];
  const int tid = threadIdx.x;
  const int bid = blockIdx.x;
  uint_t* ctxu = (uint_t*)ctxb;

  if (bid >= 32) {
    // ================= GRU role: rows 4g..4g+3 =================
    const int g = bid - 32;
    float* hstate = (float*)smem;
    float* xv     = (float*)(smem + 4096);
    float* par    = (float*)(smem + 4736);
    float* encp   = (float*)(smem + 37504);
    const int j = tid & 255, kh = tid >> 8;
    for (int i = tid; i < 1024; i += 512) hstate[i] = 0.f;
    __syncthreads();
    for (int t = 0; t < TT; ++t) {
      if (tid < 132) {
        int k = tid >> 2, r = tid & 3;
        xv[k*4 + r] = (k < 32) ? xs[((size_t)(4*g + r)*TT + t)*DD + k] : ts[t];
      }
      __syncthreads();
      {
        float pr[4]={0,0,0,0}, pu[4]={0,0,0,0}, pn[4]={0,0,0,0}, ph[4]={0,0,0,0};
        if (kh == 0) {
          #pragma unroll 3
          for (int k = 0; k < 33; ++k) {
            uint_t ru = Wgru[k*256 + j];
            float wr = bflo(ru), wu = bfhi(ru), wn = bf2f(Wgn[k*256 + j]);
            float4 a = *(const float4*)&xv[k*4];
            pr[0]+=a.x*wr; pr[1]+=a.y*wr; pr[2]+=a.z*wr; pr[3]+=a.w*wr;
            pu[0]+=a.x*wu; pu[1]+=a.y*wu; pu[2]+=a.z*wu; pu[3]+=a.w*wu;
            pn[0]+=a.x*wn; pn[1]+=a.y*wn; pn[2]+=a.z*wn; pn[3]+=a.w*wn;
          }
          #pragma unroll 4
          for (int k = 33; k < 145; ++k) {
            uint_t ru = Wgru[k*256 + j];
            float wr = bflo(ru), wu = bfhi(ru), wn = bf2f(Wgn[k*256 + j]);
            float4 a = *(const float4*)&hstate[(k-33)*4];
            pr[0]+=a.x*wr; pr[1]+=a.y*wr; pr[2]+=a.z*wr; pr[3]+=a.w*wr;
            pu[0]+=a.x*wu; pu[1]+=a.y*wu; pu[2]+=a.z*wu; pu[3]+=a.w*wu;
            ph[0]+=a.x*wn; ph[1]+=a.y*wn; ph[2]+=a.z*wn; ph[3]+=a.w*wn;
          }
        } else {
          #pragma unroll 4
          for (int k = 145; k < 289; ++k) {
            uint_t ru = Wgru[k*256 + j];
            float wr = bflo(ru), wu = bfhi(ru), wn = bf2f(Wgn[k*256 + j]);
            float4 a = *(const float4*)&hstate[(k-33)*4];
            pr[0]+=a.x*wr; pr[1]+=a.y*wr; pr[2]+=a.z*wr; pr[3]+=a.w*wr;
            pu[0]+=a.x*wu; pu[1]+=a.y*wu; pu[2]+=a.z*wu; pu[3]+=a.w*wu;
            ph[0]+=a.x*wn; ph[1]+=a.y*wn; ph[2]+=a.z*wn; ph[3]+=a.w*wn;
          }
        }
        #pragma unroll
        for (int r = 0; r < 4; ++r)
          *(float4*)&par[((kh*256 + j)*4 + r)*4] = make_float4(pr[r], pu[r], pn[r], ph[r]);
      }
      __syncthreads();
      if (tid < 256) {
        float br = grub[tid], bu = grub[256+tid], bn = grub[512+tid];
        #pragma unroll
        for (int r = 0; r < 4; ++r) {
          float4 p0 = *(const float4*)&par[((0*256 + tid)*4 + r)*4];
          float4 p1 = *(const float4*)&par[((1*256 + tid)*4 + r)*4];
          float rg = sigmoid_f(p0.x + p1.x + br);
          float ug = sigmoid_f(p0.y + p1.y + bu);
          float ng = tanhf(p0.z + p1.z + bn + rg*(p0.w + p1.w));
          hstate[tid*4 + r] = (1.f - ug)*ng + ug*hstate[tid*4 + r];
        }
      }
      __syncthreads();
      {
        int c = tid & 127, rr = (tid >> 7) & 1, khalf = tid >> 8, k0 = khalf*128;
        float accA = 0.f, accB = 0.f;
        #pragma unroll 8
        for (int k = k0; k < k0 + 128; ++k) {
          float wv = bf2f(encWb[k*CC + c]);
          accA += hstate[k*4 + rr]     * wv;
          accB += hstate[k*4 + rr + 2] * wv;
        }
        encp[(khalf*4 + rr)*128 + c]     = accA;
        encp[(khalf*4 + rr + 2)*128 + c] = accB;
      }
      __syncthreads();
      if (tid < 256) {
        int u = tid & 63, r = tid >> 6;
        int c0 = 2*u, c1 = 2*u + 1;
        float v0 = encp[(0*4 + r)*128 + c0] + encp[(1*4 + r)*128 + c0] + encb[c0];
        float v1 = encp[(0*4 + r)*128 + c1] + encp[(1*4 + r)*128 + c1] + encb[c1];
        uint_t val = (uint_t)f2bf(v0) | ((uint_t)f2bf(v1) << 16);
        __hip_atomic_store(&ctxu[((size_t)t*BB + 4*g + r)*64 + u], val,
                           __ATOMIC_RELAXED, __HIP_MEMORY_SCOPE_AGENT);
      }
      __syncthreads();
      if (tid == 0)
        __hip_atomic_fetch_add(&prog[g], 1u, __ATOMIC_RELEASE, __HIP_MEMORY_SCOPE_AGENT);
    }
    return;
  }

  // ================= SDE role =================
  const int rg = bid;
  const int b0 = rg * 16;
  const int w = tid >> 6, lane = tid & 63;
  __bf16* INp = (__bf16*)(smem + O_INP);
  __bf16* A1  = (__bf16*)(smem + O_A1);
  __bf16* A2  = (__bf16*)(smem + O_A2);
  float*  l3f = (float*)(smem + O_L3F);
  float*  l3h = (float*)(smem + O_L3H);
  ushort_t* stg = (ushort_t*)(smem + O_STG);
  ushort_t* myslot = stg + w*6656;   // 13 x 512 ushorts

  float zA, zB, dlA = 0.f, dlB = 0.f, lqA, lqB, dwA, dwB;
  uint_t known = 0;

  if (tid == 0) {
    while (known < 2u) {
      uint_t m = 0xffffffffu;
      #pragma unroll
      for (int i = 0; i < 4; ++i) {
        uint_t v = __hip_atomic_load(&prog[rg*4 + i], __ATOMIC_ACQUIRE, __HIP_MEMORY_SCOPE_AGENT);
        m = (v < m) ? v : m;
      }
      known = m;
      if (known < 2u) __builtin_amdgcn_s_sleep(8);
    }
  }
  __syncthreads();

  // ---- z0 phase ----
  {
    float* ctx0f = (float*)A1;
    float* qf    = (float*)A2;
    #pragma unroll
    for (int q = 0; q < 2; ++q) {
      int o = tid + q*512;
      int r = o >> 6, u = o & 63;
      uint_t v = __hip_atomic_load(&ctxu[(size_t)(b0 + r)*64 + u], __ATOMIC_RELAXED, __HIP_MEMORY_SCOPE_AGENT);
      ctx0f[r*128 + 2*u]     = bflo(v);
      ctx0f[r*128 + 2*u + 1] = bfhi(v);
    }
    __syncthreads();
    #pragma unroll
    for (int q = 0; q < 4; ++q) {
      int o = tid + q*512;
      int r = o >> 7, n = o & 127;
      float acc = qzb[n];
      #pragma unroll 4
      for (int k = 0; k < CC; ++k) acc += ctx0f[r*128 + k]*qzW[k*128 + n];
      qf[o] = acc;
    }
    __syncthreads();
    #pragma unroll
    for (int e = 0; e < 2; ++e) {
      int r = w + e*8, l = lane;
      float qm  = qf[r*128 + l];
      float qls = fminf(fmaxf(qf[r*128 + 64 + l], -20.f), 2.f);
      float z0  = qm + __expf(qls)*eps0[(size_t)(b0+r)*LL + l];
      if (e == 0) zA = z0; else zB = z0;
      INp[AP_SCAT(r, l)] = (__bf16)z0;
      float dp = (z0 - pm[l])*__expf(-pls[l]);
      float dq = (z0 - qm)*__expf(-qls);
      float v = (-0.5f*dp*dp - pls[l]) - (-0.5f*dq*dq - qls);
      #pragma unroll
      for (int off = 1; off < 64; off <<= 1) v += __shfl_xor(v, off);
      if (e == 0) lqA = v; else lqB = v;
    }
    #pragma unroll
    for (int q = 0; q < 2; ++q) {
      int o = tid + q*512;
      int r = o >> 6, u = o & 63;
      uint_t v = __hip_atomic_load(&ctxu[((size_t)1*BB + b0 + r)*64 + u], __ATOMIC_RELAXED, __HIP_MEMORY_SCOPE_AGENT);
      INp[AP_SCAT(r, 64 + 2*u)]     = bfbits((ushort_t)(v & 0xffffu));
      INp[AP_SCAT(r, 64 + 2*u + 1)] = bfbits((ushort_t)(v >> 16));
    }
    dwA = dW[((size_t)0*BB + b0 + w)*LL + lane];
    dwB = dW[((size_t)0*BB + b0 + w + 8)*LL + lane];
    __syncthreads();
    if (w < 2) {
      f32x4 pc = {0,0,0,0};
      bf16x8 a0 = *(const bf16x8*)(INp + lane*8);
      bf16x8 b0f = *(const bf16x8*)(projWp + (size_t)(0*2 + w)*512 + lane*8);
      pc = MFMA_B16(a0, b0f, pc);
      bf16x8 a1 = *(const bf16x8*)(INp + 512 + lane*8);
      bf16x8 b1f = *(const bf16x8*)(projWp + (size_t)(1*2 + w)*512 + lane*8);
      pc = MFMA_B16(a1, b1f, pc);
      int col = w*16 + (lane & 15);
      float pb = projb[col];
      #pragma unroll
      for (int j = 0; j < 4; ++j) {
        int row = ((lane>>4)<<2) + j;
        out[((size_t)(b0+row)*TT + 0)*DD + col] = pc[j] + pb;
      }
    }
    __syncthreads();
  }

  // ---- SDE scan ----
  for (int t = 0; t < TT-1; ++t) {
    // P1h (N=8, depth-8)
    {
      f32x4 acc[4] = {{0,0,0,0},{0,0,0,0},{0,0,0,0},{0,0,0,0}};
      phase4d8<2>(W1hp, w*4, INp, myslot, lane, acc);
      #pragma unroll
      for (int i = 0; i < 4; ++i) {
        int c = ((w*4 + i)<<4) + (lane & 15);
        float bv = hb1[c];
        #pragma unroll
        for (int j = 0; j < 4; ++j)
          A1[AP_SCAT(((lane>>4)<<2) + j, c)] = (__bf16)softplus_f(acc[i][j] + bv);
      }
    }
    __syncthreads();
    // P2h (N=64, depth-12)
    {
      f32x4 acc[4] = {{0,0,0,0},{0,0,0,0},{0,0,0,0},{0,0,0,0}};
      phase4d12<16>(W2hp, w*4, A1, myslot, lane, acc);
      #pragma unroll
      for (int i = 0; i < 4; ++i) {
        int c = ((w*4 + i)<<4) + (lane & 15);
        float bv = hb2[c];
        #pragma unroll
        for (int j = 0; j < 4; ++j)
          A2[AP_SCAT(((lane>>4)<<2) + j, c)] = (__bf16)softplus_f(acc[i][j] + bv);
      }
    }
    __syncthreads();
    // P3h
    if (w < 4) {
      f32x4 acc = {0,0,0,0};
      phase1<16,4>(W3hp, w, A2, myslot, lane, acc);
      int cl = (w<<4) + (lane & 15);
      float bv = hb3[cl];
      #pragma unroll
      for (int j = 0; j < 4; ++j)
        l3h[(((lane>>4)<<2) + j)*64 + cl] = acc[j] + bv;
    }
    __syncthreads();
    // P1f (N=24, depth-12)
    {
      f32x4 acc[4] = {{0,0,0,0},{0,0,0,0},{0,0,0,0},{0,0,0,0}};
      phase4d12<6>(W1fp, w*4, INp, myslot, lane, acc);
      #pragma unroll
      for (int i = 0; i < 4; ++i) {
        int c = ((w*4 + i)<<4) + (lane & 15);
        float bv = fb1[c];
        #pragma unroll
        for (int j = 0; j < 4; ++j)
          A1[AP_SCAT(((lane>>4)<<2) + j, c)] = (__bf16)softplus_f(acc[i][j] + bv);
      }
    }
    __syncthreads();
    // P2f (N=64, depth-12)
    {
      f32x4 acc[4] = {{0,0,0,0},{0,0,0,0},{0,0,0,0},{0,0,0,0}};
      phase4d12<16>(W2fp, w*4, A1, myslot, lane, acc);
      #pragma unroll
      for (int i = 0; i < 4; ++i) {
        int c = ((w*4 + i)<<4) + (lane & 15);
        float bv = fb2[c];
        #pragma unroll
        for (int j = 0; j < 4; ++j)
          A2[AP_SCAT(((lane>>4)<<2) + j, c)] = (__bf16)softplus_f(acc[i][j] + bv);
      }
    }
    __syncthreads();
    // P3f
    if (w < 4) {
      f32x4 acc = {0,0,0,0};
      phase1<16,4>(W3fp, w, A2, myslot, lane, acc);
      int cl = (w<<4) + (lane & 15);
      float bv = fb3[cl];
      #pragma unroll
      for (int j = 0; j < 4; ++j)
        l3f[(((lane>>4)<<2) + j)*64 + cl] = acc[j] + bv;
    }
    __syncthreads();

    // wait for ctx[t+2] availability before prefetch
    if (t + 2 < TT) {
      if (tid == 0 && known < (uint_t)(t+3)) {
        while (known < (uint_t)(t+3)) {
          uint_t m = 0xffffffffu;
          #pragma unroll
          for (int i = 0; i < 4; ++i) {
            uint_t v = __hip_atomic_load(&prog[rg*4 + i], __ATOMIC_ACQUIRE, __HIP_MEMORY_SCOPE_AGENT);
            m = (v < m) ? v : m;
          }
          known = m;
          if (known < (uint_t)(t+3)) __builtin_amdgcn_s_sleep(4);
        }
      }
      __syncthreads();
    }

    // ---- epilogue ----
    {
      float t0 = ts[t], t1 = ts[t+1];
      float dt = t1 - t0;
      float sqdt = sqrtf(dt);
      float sqA, sqB;
      #pragma unroll
      for (int e = 0; e < 2; ++e) {
        int r = w + e*8, l = lane;
        float zv = e ? zB : zA;
        float gz;
        if (__builtin_expect(fabsf(zv) < 63.9f, 1)) {
          float x = (zv - GZMIN)*GSCALE;
          int jx = (int)x;
          float fr = x - (float)jx;
          const float* gt = &gtab[l*GK + jx];
          float g0v = gt[0], g1v = gt[1];
          gz = g0v + (g1v - g0v)*fr;
        } else {
          float s = 0.f;
          for (int h = 0; h < 512; ++h)
            s += softplus_f(zv*gw1[l*512+h] + gb1[l*512+h]) * gw2[l*512+h];
          gz = sigmoid_f(s + gb2[l]);
        }
        float fzv = l3f[r*64 + l], hzv = l3h[r*64 + l];
        float u = (fzv - hzv)/gz;
        float sq = u*u;
        #pragma unroll
        for (int off = 1; off < 64; off <<= 1) sq += __shfl_xor(sq, off);
        float zn = zv + fzv*dt + gz*sqdt*(e ? dwB : dwA);
        if (e == 0) { sqA = sq; zA = zn; } else { sqB = sq; zB = zn; }
        INp[AP_SCAT(r, l)] = (__bf16)zn;
      }
      dlA += 0.5f*sqA*dt;
      dlB += 0.5f*sqB*dt;
      if (t + 2 < TT) {
        #pragma unroll
        for (int q = 0; q < 2; ++q) {
          int o = tid + q*512;
          int r = o >> 6, u = o & 63;
          uint_t v = __hip_atomic_load(&ctxu[((size_t)(t+2)*BB + b0 + r)*64 + u], __ATOMIC_RELAXED, __HIP_MEMORY_SCOPE_AGENT);
          INp[AP_SCAT(r, 64 + 2*u)]     = bfbits((ushort_t)(v & 0xffffu));
          INp[AP_SCAT(r, 64 + 2*u + 1)] = bfbits((ushort_t)(v >> 16));
        }
      }
      if (t + 1 < TT-1) {
        dwA = dW[((size_t)(t+1)*BB + b0 + w)*LL + lane];
        dwB = dW[((size_t)(t+1)*BB + b0 + w + 8)*LL + lane];
      }
    }
    __syncthreads();

    // proj of z_{t+1}
    if (w < 2) {
      f32x4 pc = {0,0,0,0};
      bf16x8 a0 = *(const bf16x8*)(INp + lane*8);
      bf16x8 b0f = *(const bf16x8*)(projWp + (size_t)(0*2 + w)*512 + lane*8);
      pc = MFMA_B16(a0, b0f, pc);
      bf16x8 a1 = *(const bf16x8*)(INp + 512 + lane*8);
      bf16x8 b1f = *(const bf16x8*)(projWp + (size_t)(1*2 + w)*512 + lane*8);
      pc = MFMA_B16(a1, b1f, pc);
      int col = w*16 + (lane & 15);
      float pb = projb[col];
      #pragma unroll
      for (int j = 0; j < 4; ++j) {
        int row = ((lane>>4)<<2) + j;
        out[((size_t)(b0+row)*TT + (t+1))*DD + col] = pc[j] + pb;
      }
    }
  }

  if (lane == 0) {
    out[(size_t)BB*TT*DD + b0 + w]     = lqA - dlA;
    out[(size_t)BB*TT*DD + b0 + w + 8] = lqB - dlB;
  }
}

extern "C" void kernel_launch(void* const* d_in, const int* in_sizes, int n_in,
                              void* d_out, int out_size, void* d_ws, size_t ws_size,
                              hipStream_t stream)
{
  const float* xs   = (const float*)d_in[0];
  const float* ts   = (const float*)d_in[1];
  const float* eps0 = (const float*)d_in[2];
  const float* dW   = (const float*)d_in[3];
  const float* gruWx= (const float*)d_in[4];
  const float* gruWh= (const float*)d_in[5];
  const float* grub = (const float*)d_in[6];
  const float* encW = (const float*)d_in[7];
  const float* encb = (const float*)d_in[8];
  const float* qzW  = (const float*)d_in[9];
  const float* qzb  = (const float*)d_in[10];
  const float* fW1  = (const float*)d_in[11];
  const float* fb1  = (const float*)d_in[12];
  const float* fW2  = (const float*)d_in[13];
  const float* fb2  = (const float*)d_in[14];
  const float* fW3  = (const float*)d_in[15];
  const float* fb3  = (const float*)d_in[16];
  const float* hW1  = (const float*)d_in[17];
  const float* hb1  = (const float*)d_in[18];
  const float* hW2  = (const float*)d_in[19];
  const float* hb2  = (const float*)d_in[20];
  const float* hW3  = (const float*)d_in[21];
  const float* hb3  = (const float*)d_in[22];
  const float* gw1  = (const float*)d_in[23];
  const float* gb1  = (const float*)d_in[24];
  const float* gw2  = (const float*)d_in[25];
  const float* gb2  = (const float*)d_in[26];
  const float* projW= (const float*)d_in[27];
  const float* projb= (const float*)d_in[28];
  const float* pm   = (const float*)d_in[29];
  const float* pls  = (const float*)d_in[30];
  float* out = (float*)d_out;

  ushort_t* ctxb = (ushort_t*)d_ws;
  float* gtab    = (float*)(ctxb + 16777216);
  ushort_t* W1fp = (ushort_t*)(gtab + 262208);
  ushort_t* W1hp = W1fp + 98304;
  ushort_t* W2fp = W1hp + 32768;
  ushort_t* W2hp = W2fp + 262144;
  ushort_t* W3fp = W2hp + 262144;
  ushort_t* W3hp = W3fp + 32768;
  ushort_t* encWb= W3hp + 32768;
  uint_t*   Wgru = (uint_t*)(encWb + 32768);
  ushort_t* Wgn  = (ushort_t*)(Wgru + 73984);
  ushort_t* projWp = Wgn + 73984;
  uint_t* prog   = (uint_t*)(projWp + 2048);

  hipLaunchKernelGGL(prep_kernel, dim3(3241), dim3(256), 0, stream,
                     fW1, hW1, fW2, hW2, fW3, hW3, gruWx, gruWh, encW, projW,
                     W1fp, W1hp, W2fp, W2hp, W3fp, W3hp, encWb, Wgru, Wgn, projWp);
  hipLaunchKernelGGL(lut_kernel, dim3(1025), dim3(256), 0, stream,
                     gw1, gb1, gw2, gb2, gtab);
  hipMemsetAsync(prog, 0, 128*sizeof(uint_t), stream);
  hipLaunchKernelGGL(mega_kernel, dim3(160), dim3(512), 0, stream,
                     xs, ts, eps0, dW, qzW, qzb, pm, pls,
                     W1fp, W1hp, W2fp, W2hp, W3fp, W3hp,
                     fb1, hb1, fb2, hb2, fb3, hb3,
                     gtab, gw1, gb1, gw2, gb2,
                     Wgru, Wgn, grub, encWb, encb, projWp, projb,
                     ctxb, prog, out);
}

// Round 18
// 6619.659 us; speedup vs baseline: 1.6878x; 1.6878x over previous
//
#include <hip/hip_runtime.h>
#include <math.h>

typedef unsigned int uint_t;
typedef unsigned short ushort_t;
typedef __bf16 bf16x8 __attribute__((ext_vector_type(8)));
typedef float f32x4 __attribute__((ext_vector_type(4)));

#define BB 512
#define TT 256
#define DD 32
#define LL 64
#define CC 128
#define HH 512
#define HE 256
#define LOG2PI_ 1.8378770664093453f
#define GK 4097
#define GSCALE 32.0f
#define GZMIN (-64.0f)

__device__ __forceinline__ float softplus_f(float x) {
  float ax = fabsf(x);
  return fmaxf(x, 0.0f) + __logf(1.0f + __expf(-ax));
}
__device__ __forceinline__ float sigmoid_f(float x) {
  return 1.0f / (1.0f + __expf(-x));
}
__device__ __forceinline__ float bf2f(ushort_t s) {
  return __uint_as_float(((uint_t)s) << 16);
}
__device__ __forceinline__ float bflo(uint_t u) { return __uint_as_float(u << 16); }
__device__ __forceinline__ float bfhi(uint_t u) { return __uint_as_float(u & 0xffff0000u); }
__device__ __forceinline__ ushort_t f2bf(float f) {
  uint_t u = __float_as_uint(f);
  return (ushort_t)((u + 0x7fffu + ((u >> 16) & 1u)) >> 16);
}
__device__ __forceinline__ __bf16 bfbits(ushort_t v) {
  __bf16 b; *(ushort_t*)&b = v; return b;
}

#define MFMA_B16(a,b,c) __builtin_amdgcn_mfma_f32_16x16x32_bf16(a,b,c,0,0,0)

// async global->LDS, 16B per lane; aux=1 (sc0): neutral, kept from r16.
__device__ __forceinline__ void gld16(const ushort_t* g, ushort_t* l) {
  __builtin_amdgcn_global_load_lds(
      (const __attribute__((address_space(1))) unsigned int*)(const void*)g,
      (__attribute__((address_space(3))) unsigned int*)(void*)l, 16, 0, 1);
}

// ---------------- prep: pack weights into MFMA fragment order ---------------
__global__ void prep_kernel(
    const float* __restrict__ fW1, const float* __restrict__ hW1,
    const float* __restrict__ fW2, const float* __restrict__ hW2,
    const float* __restrict__ fW3, const float* __restrict__ hW3,
    const float* __restrict__ Wx,  const float* __restrict__ Wh,
    const float* __restrict__ encW, const float* __restrict__ projW,
    ushort_t* __restrict__ W1fp, ushort_t* __restrict__ W1hp,
    ushort_t* __restrict__ W2fp, ushort_t* __restrict__ W2hp,
    ushort_t* __restrict__ W3fp, ushort_t* __restrict__ W3hp,
    ushort_t* __restrict__ encWb,
    uint_t* __restrict__ Wgru, ushort_t* __restrict__ Wgn,
    ushort_t* __restrict__ projWp)
{
  int idx = blockIdx.x*256 + threadIdx.x;
  if (idx < 98304) {
    int f = idx >> 9, e = idx & 511;
    int ks = f >> 5, nt = f & 31, l = e >> 3, j = e & 7;
    int k = ks*32 + ((l>>4)<<3) + j, n = nt*16 + (l & 15);
    W1fp[idx] = f2bf(fW1[k*512 + n]);
  } else if (idx < 131072) {
    int r = idx - 98304;
    int f = r >> 9, e = r & 511;
    int ks = f >> 5, nt = f & 31, l = e >> 3, j = e & 7;
    int k = ks*32 + ((l>>4)<<3) + j, n = nt*16 + (l & 15);
    W1hp[r] = f2bf(hW1[k*512 + n]);
  } else if (idx < 393216) {
    int r = idx - 131072;
    int f = r >> 9, e = r & 511;
    int ks = f >> 5, nt = f & 31, l = e >> 3, j = e & 7;
    int k = ks*32 + ((l>>4)<<3) + j, n = nt*16 + (l & 15);
    W2fp[r] = f2bf(fW2[k*512 + n]);
  } else if (idx < 655360) {
    int r = idx - 393216;
    int f = r >> 9, e = r & 511;
    int ks = f >> 5, nt = f & 31, l = e >> 3, j = e & 7;
    int k = ks*32 + ((l>>4)<<3) + j, n = nt*16 + (l & 15);
    W2hp[r] = f2bf(hW2[k*512 + n]);
  } else if (idx < 688128) {
    int r = idx - 655360;
    int f = r >> 9, e = r & 511;
    int ks = f >> 2, nt = f & 3, l = e >> 3, j = e & 7;
    int k = ks*32 + ((l>>4)<<3) + j, n = nt*16 + (l & 15);
    W3fp[r] = f2bf(fW3[k*64 + n]);
  } else if (idx < 720896) {
    int r = idx - 688128;
    int f = r >> 9, e = r & 511;
    int ks = f >> 2, nt = f & 3, l = e >> 3, j = e & 7;
    int k = ks*32 + ((l>>4)<<3) + j, n = nt*16 + (l & 15);
    W3hp[r] = f2bf(hW3[k*64 + n]);
  } else if (idx < 753664) {
    int r = idx - 720896;
    encWb[r] = f2bf(encW[r]);
  } else if (idx < 827648) {
    int r = idx - 753664;
    int k = r >> 8, j = r & 255;
    float wr, wu, wn;
    if (k < 33) { wr = Wx[k*768 + j]; wu = Wx[k*768 + 256 + j]; wn = Wx[k*768 + 512 + j]; }
    else { int kk = k - 33; wr = Wh[kk*768 + j]; wu = Wh[kk*768 + 256 + j]; wn = Wh[kk*768 + 512 + j]; }
    Wgru[r] = (uint_t)f2bf(wr) | ((uint_t)f2bf(wu) << 16);
    Wgn[r]  = f2bf(wn);
  } else if (idx < 829696) {
    int r = idx - 827648;
    int f = r >> 9, e = r & 511;
    int ks = f >> 1, nt = f & 1, l = e >> 3, j = e & 7;
    int k = ks*32 + ((l>>4)<<3) + j, n = nt*16 + (l & 15);
    projWp[r] = f2bf(projW[k*32 + n]);
  }
}

// ---------------- g-function lookup table -----------------------------------
__global__ void lut_kernel(const float* __restrict__ gw1, const float* __restrict__ gb1,
                           const float* __restrict__ gw2, const float* __restrict__ gb2,
                           float* __restrict__ gtab)
{
  int idx = blockIdx.x*256 + threadIdx.x;
  if (idx >= 64*GK) return;
  int l = idx / GK, i = idx - l*GK;
  float z = GZMIN + (float)i*(1.0f/GSCALE);
  float s = 0.f;
  for (int h = 0; h < 512; ++h)
    s += softplus_f(z*gw1[l*512+h] + gb1[l*512+h]) * gw2[l*512+h];
  gtab[idx] = sigmoid_f(s + gb2[l]);
}

// ---------------- r11-proven SDE pipelines -----------------------------------
#define AP_SCAT(row,k) (((k)>>5)*512 + ((row) + ((((k)>>3)&3)<<4))*8 + ((k)&7))

#define O_INP  0         // 6144
#define O_A1   6144      // 16384
#define O_A2   22528     // 16384
#define O_L3F  38912     // 4096
#define O_L3H  43008     // 4096
#define O_STG  47104     // 73728: 8 waves x (8 ring + 1 trash) x 1KB
#define SMEM_SZ 120832

template<int KS>
__device__ __forceinline__ void phase4(
    const ushort_t* __restrict__ Wb, int nt0,
    const __bf16* __restrict__ A, ushort_t* __restrict__ slot, int lane, f32x4* acc)
{
  constexpr int N = KS*4;
  const size_t lo = (size_t)lane*8;
  #define GA4(f_) (Wb + (((size_t)(((((f_)<N?(f_):N-1))>>2)*32 + nt0 + ((((f_)<N?(f_):N-1))&3)))<<9) + lo)
  #define SL(f_)  (slot + (((f_) < N) ? (((f_)&7)*512) : (8*512)))
  #pragma unroll
  for (int d = 0; d < 8; ++d) gld16(GA4(d), slot + d*512);
  bf16x8 a  = *(const bf16x8*)(A + lo);
  bf16x8 an = a;
  asm volatile("s_waitcnt vmcnt(7)":::"memory");
  bf16x8 p0 = *(const bf16x8*)(slot + 0*512 + lo);
  asm volatile("s_waitcnt vmcnt(6)":::"memory");
  bf16x8 p1 = *(const bf16x8*)(slot + 1*512 + lo);
  bf16x8 p2, p3;
  for (int f0 = 0; f0 < N; f0 += 4) {
    int ks = f0 >> 2;
    asm volatile("s_waitcnt vmcnt(5)":::"memory");
    p2 = *(const bf16x8*)(slot + ((f0+2)&7)*512 + lo);
    asm volatile("s_waitcnt lgkmcnt(2)":::"memory");
    gld16(GA4(f0+8), SL(f0+8));
    acc[0] = MFMA_B16(a, p0, acc[0]);
    asm volatile("s_waitcnt vmcnt(5)":::"memory");
    p3 = *(const bf16x8*)(slot + ((f0+3)&7)*512 + lo);
    asm volatile("s_waitcnt lgkmcnt(2)":::"memory");
    gld16(GA4(f0+9), SL(f0+9));
    acc[1] = MFMA_B16(a, p1, acc[1]);
    asm volatile("s_waitcnt vmcnt(5)":::"memory");
    p0 = *(const bf16x8*)(slot + ((f0+4)&7)*512 + lo);
    if (ks + 1 < KS) an = *(const bf16x8*)(A + ((size_t)(ks+1)<<9) + lo);
    asm volatile("s_waitcnt lgkmcnt(3)":::"memory");
    gld16(GA4(f0+10), SL(f0+10));
    acc[2] = MFMA_B16(a, p2, acc[2]);
    asm volatile("s_waitcnt vmcnt(5)":::"memory");
    p1 = *(const bf16x8*)(slot + ((f0+5)&7)*512 + lo);
    asm volatile("s_waitcnt lgkmcnt(3)":::"memory");
    gld16(GA4(f0+11), SL(f0+11));
    acc[3] = MFMA_B16(a, p3, acc[3]);
    a = an;
  }
  #undef GA4
  #undef SL
}

template<int KS, int NTS>
__device__ __forceinline__ void phase1(
    const ushort_t* __restrict__ Wb, int nt,
    const __bf16* __restrict__ A, ushort_t* __restrict__ slot, int lane, f32x4& acc)
{
  constexpr int N = KS;
  const size_t lo = (size_t)lane*8;
  #define GA1(f_) (Wb + (((size_t)((((f_)<N?(f_):N-1))*NTS + nt))<<9) + lo)
  #define SL1(f_)  (slot + (((f_) < N) ? (((f_)&7)*512) : (8*512)))
  #define QA(f_)  (*(const bf16x8*)(A + ((size_t)(((f_)<N?(f_):N-1))<<9) + lo))
  #pragma unroll
  for (int d = 0; d < 8; ++d) gld16(GA1(d), slot + d*512);
  bf16x8 q0 = QA(0);
  asm volatile("s_waitcnt vmcnt(7)":::"memory");
  bf16x8 p0 = *(const bf16x8*)(slot + 0*512 + lo);
  bf16x8 q1 = QA(1);
  asm volatile("s_waitcnt vmcnt(6)":::"memory");
  bf16x8 p1 = *(const bf16x8*)(slot + 1*512 + lo);
  bf16x8 p2, p3, q2, q3;
  for (int f0 = 0; f0 < N; f0 += 4) {
    q2 = QA(f0+2);
    asm volatile("s_waitcnt vmcnt(5)":::"memory");
    p2 = *(const bf16x8*)(slot + ((f0+2)&7)*512 + lo);
    asm volatile("s_waitcnt lgkmcnt(4)":::"memory");
    gld16(GA1(f0+8), SL1(f0+8));
    acc = MFMA_B16(q0, p0, acc);
    q3 = QA(f0+3);
    asm volatile("s_waitcnt vmcnt(5)":::"memory");
    p3 = *(const bf16x8*)(slot + ((f0+3)&7)*512 + lo);
    asm volatile("s_waitcnt lgkmcnt(4)":::"memory");
    gld16(GA1(f0+9), SL1(f0+9));
    acc = MFMA_B16(q1, p1, acc);
    q0 = QA(f0+4);
    asm volatile("s_waitcnt vmcnt(5)":::"memory");
    p0 = *(const bf16x8*)(slot + ((f0+4)&7)*512 + lo);
    asm volatile("s_waitcnt lgkmcnt(4)":::"memory");
    gld16(GA1(f0+10), SL1(f0+10));
    acc = MFMA_B16(q2, p2, acc);
    q1 = QA(f0+5);
    asm volatile("s_waitcnt vmcnt(5)":::"memory");
    p1 = *(const bf16x8*)(slot + ((f0+5)&7)*512 + lo);
    asm volatile("s_waitcnt lgkmcnt(4)":::"memory");
    gld16(GA1(f0+11), SL1(f0+11));
    acc = MFMA_B16(q3, p3, acc);
  }
  #undef GA1
  #undef SL1
  #undef QA
}

// ---------------- mega kernel: 32 SDE blocks + 128 GRU blocks ---------------
__global__ __launch_bounds__(512) void mega_kernel(
  const float* __restrict__ xs, const float* __restrict__ ts,
  const float* __restrict__ eps0, const float* __restrict__ dW,
  const float* __restrict__ qzW, const float* __restrict__ qzb,
  const float* __restrict__ pm, const float* __restrict__ pls,
  const ushort_t* __restrict__ W1fp, const ushort_t* __restrict__ W1hp,
  const ushort_t* __restrict__ W2fp, const ushort_t* __restrict__ W2hp,
  const ushort_t* __restrict__ W3fp, const ushort_t* __restrict__ W3hp,
  const float* __restrict__ fb1, const float* __restrict__ hb1,
  const float* __restrict__ fb2, const float* __restrict__ hb2,
  const float* __restrict__ fb3, const float* __restrict__ hb3,
  const float* __restrict__ gtab,
  const float* __restrict__ gw1, const float* __restrict__ gb1,
  const float* __restrict__ gw2, const float* __restrict__ gb2,
  const uint_t* __restrict__ Wgru, const ushort_t* __restrict__ Wgn,
  const float* __restrict__ grub,
  const ushort_t* __restrict__ encWb, const float* __restrict__ encb,
  const ushort_t* __restrict__ projWp, const float* __restrict__ projb,
  ushort_t* __restrict__ ctxb, uint_t* __restrict__ prog,
  float* __restrict__ out)
{
  __shared__ __align__(16) unsigned char smem[SMEM_SZ];
  const int tid = threadIdx.x;
  const int bid = blockIdx.x;
  uint_t* ctxu = (uint_t*)ctxb;

  if (bid >= 32) {
    // ================= GRU role: rows 4g..4g+3 =================
    const int g = bid - 32;
    float* hstate = (float*)smem;                    // [256][4]
    float* xv     = (float*)(smem + 4096);           // [33][4]
    float* par    = (float*)(smem + 4736);           // [2][256][4][4]
    float* encp   = (float*)(smem + 37504);          // [2][4][128]
    const int j = tid & 255, kh = tid >> 8;
    for (int i = tid; i < 1024; i += 512) hstate[i] = 0.f;
    __syncthreads();
    for (int t = 0; t < TT; ++t) {
      if (tid < 132) {
        int k = tid >> 2, r = tid & 3;
        xv[k*4 + r] = (k < 32) ? xs[((size_t)(4*g + r)*TT + t)*DD + k] : ts[t];
      }
      __syncthreads();
      {
        float pr[4]={0,0,0,0}, pu[4]={0,0,0,0}, pn[4]={0,0,0,0}, ph[4]={0,0,0,0};
        if (kh == 0) {
          #pragma unroll 3
          for (int k = 0; k < 33; ++k) {
            uint_t ru = Wgru[k*256 + j];
            float wr = bflo(ru), wu = bfhi(ru), wn = bf2f(Wgn[k*256 + j]);
            float4 a = *(const float4*)&xv[k*4];
            pr[0]+=a.x*wr; pr[1]+=a.y*wr; pr[2]+=a.z*wr; pr[3]+=a.w*wr;
            pu[0]+=a.x*wu; pu[1]+=a.y*wu; pu[2]+=a.z*wu; pu[3]+=a.w*wu;
            pn[0]+=a.x*wn; pn[1]+=a.y*wn; pn[2]+=a.z*wn; pn[3]+=a.w*wn;
          }
          #pragma unroll 4
          for (int k = 33; k < 145; ++k) {
            uint_t ru = Wgru[k*256 + j];
            float wr = bflo(ru), wu = bfhi(ru), wn = bf2f(Wgn[k*256 + j]);
            float4 a = *(const float4*)&hstate[(k-33)*4];
            pr[0]+=a.x*wr; pr[1]+=a.y*wr; pr[2]+=a.z*wr; pr[3]+=a.w*wr;
            pu[0]+=a.x*wu; pu[1]+=a.y*wu; pu[2]+=a.z*wu; pu[3]+=a.w*wu;
            ph[0]+=a.x*wn; ph[1]+=a.y*wn; ph[2]+=a.z*wn; ph[3]+=a.w*wn;
          }
        } else {
          #pragma unroll 4
          for (int k = 145; k < 289; ++k) {
            uint_t ru = Wgru[k*256 + j];
            float wr = bflo(ru), wu = bfhi(ru), wn = bf2f(Wgn[k*256 + j]);
            float4 a = *(const float4*)&hstate[(k-33)*4];
            pr[0]+=a.x*wr; pr[1]+=a.y*wr; pr[2]+=a.z*wr; pr[3]+=a.w*wr;
            pu[0]+=a.x*wu; pu[1]+=a.y*wu; pu[2]+=a.z*wu; pu[3]+=a.w*wu;
            ph[0]+=a.x*wn; ph[1]+=a.y*wn; ph[2]+=a.z*wn; ph[3]+=a.w*wn;
          }
        }
        #pragma unroll
        for (int r = 0; r < 4; ++r)
          *(float4*)&par[((kh*256 + j)*4 + r)*4] = make_float4(pr[r], pu[r], pn[r], ph[r]);
      }
      __syncthreads();
      if (tid < 256) {
        float br = grub[tid], bu = grub[256+tid], bn = grub[512+tid];
        #pragma unroll
        for (int r = 0; r < 4; ++r) {
          float4 p0 = *(const float4*)&par[((0*256 + tid)*4 + r)*4];
          float4 p1 = *(const float4*)&par[((1*256 + tid)*4 + r)*4];
          float rg = sigmoid_f(p0.x + p1.x + br);
          float ug = sigmoid_f(p0.y + p1.y + bu);
          float ng = tanhf(p0.z + p1.z + bn + rg*(p0.w + p1.w));
          hstate[tid*4 + r] = (1.f - ug)*ng + ug*hstate[tid*4 + r];
        }
      }
      __syncthreads();
      {
        int c = tid & 127, rr = (tid >> 7) & 1, khalf = tid >> 8, k0 = khalf*128;
        float accA = 0.f, accB = 0.f;
        #pragma unroll 8
        for (int k = k0; k < k0 + 128; ++k) {
          float wv = bf2f(encWb[k*CC + c]);
          accA += hstate[k*4 + rr]     * wv;
          accB += hstate[k*4 + rr + 2] * wv;
        }
        encp[(khalf*4 + rr)*128 + c]     = accA;
        encp[(khalf*4 + rr + 2)*128 + c] = accB;
      }
      __syncthreads();
      if (tid < 256) {
        int u = tid & 63, r = tid >> 6;
        int c0 = 2*u, c1 = 2*u + 1;
        float v0 = encp[(0*4 + r)*128 + c0] + encp[(1*4 + r)*128 + c0] + encb[c0];
        float v1 = encp[(0*4 + r)*128 + c1] + encp[(1*4 + r)*128 + c1] + encb[c1];
        uint_t val = (uint_t)f2bf(v0) | ((uint_t)f2bf(v1) << 16);
        __hip_atomic_store(&ctxu[((size_t)t*BB + 4*g + r)*64 + u], val,
                           __ATOMIC_RELAXED, __HIP_MEMORY_SCOPE_AGENT);
      }
      __syncthreads();
      if (tid == 0)
        __hip_atomic_fetch_add(&prog[g], 1u, __ATOMIC_RELEASE, __HIP_MEMORY_SCOPE_AGENT);
    }
    return;
  }

  // ================= SDE role: rows 16*bid.. =================
  const int rg = bid;
  const int b0 = rg * 16;
  const int w = tid >> 6, lane = tid & 63;
  __bf16* INp = (__bf16*)(smem + O_INP);
  __bf16* A1  = (__bf16*)(smem + O_A1);
  __bf16* A2  = (__bf16*)(smem + O_A2);
  float*  l3f = (float*)(smem + O_L3F);
  float*  l3h = (float*)(smem + O_L3H);
  ushort_t* stg = (ushort_t*)(smem + O_STG);
  ushort_t* myslot = stg + w*4608;

  float zA, zB, dlA = 0.f, dlB = 0.f, lqA, lqB, dwA, dwB;
  uint_t known = 0;

  // wait for ctx[0..1]
  if (tid == 0) {
    while (known < 2u) {
      uint_t m = 0xffffffffu;
      #pragma unroll
      for (int i = 0; i < 4; ++i) {
        uint_t v = __hip_atomic_load(&prog[rg*4 + i], __ATOMIC_ACQUIRE, __HIP_MEMORY_SCOPE_AGENT);
        m = (v < m) ? v : m;
      }
      known = m;
      if (known < 2u) __builtin_amdgcn_s_sleep(8);
    }
  }
  __syncthreads();

  // ---- z0 phase ----
  {
    float* ctx0f = (float*)A1;
    float* qf    = (float*)A2;
    #pragma unroll
    for (int q = 0; q < 2; ++q) {
      int o = tid + q*512;
      int r = o >> 6, u = o & 63;
      uint_t v = __hip_atomic_load(&ctxu[(size_t)(b0 + r)*64 + u], __ATOMIC_RELAXED, __HIP_MEMORY_SCOPE_AGENT);
      ctx0f[r*128 + 2*u]     = bflo(v);
      ctx0f[r*128 + 2*u + 1] = bfhi(v);
    }
    __syncthreads();
    #pragma unroll
    for (int q = 0; q < 4; ++q) {
      int o = tid + q*512;
      int r = o >> 7, n = o & 127;
      float acc = qzb[n];
      #pragma unroll 4
      for (int k = 0; k < CC; ++k) acc += ctx0f[r*128 + k]*qzW[k*128 + n];
      qf[o] = acc;
    }
    __syncthreads();
    #pragma unroll
    for (int e = 0; e < 2; ++e) {
      int r = w + e*8, l = lane;
      float qm  = qf[r*128 + l];
      float qls = fminf(fmaxf(qf[r*128 + 64 + l], -20.f), 2.f);
      float z0  = qm + __expf(qls)*eps0[(size_t)(b0+r)*LL + l];
      if (e == 0) zA = z0; else zB = z0;
      INp[AP_SCAT(r, l)] = (__bf16)z0;
      float dp = (z0 - pm[l])*__expf(-pls[l]);
      float dq = (z0 - qm)*__expf(-qls);
      float v = (-0.5f*dp*dp - pls[l]) - (-0.5f*dq*dq - qls);
      #pragma unroll
      for (int off = 1; off < 64; off <<= 1) v += __shfl_xor(v, off);
      if (e == 0) lqA = v; else lqB = v;
    }
    #pragma unroll
    for (int q = 0; q < 2; ++q) {
      int o = tid + q*512;
      int r = o >> 6, u = o & 63;
      uint_t v = __hip_atomic_load(&ctxu[((size_t)1*BB + b0 + r)*64 + u], __ATOMIC_RELAXED, __HIP_MEMORY_SCOPE_AGENT);
      INp[AP_SCAT(r, 64 + 2*u)]     = bfbits((ushort_t)(v & 0xffffu));
      INp[AP_SCAT(r, 64 + 2*u + 1)] = bfbits((ushort_t)(v >> 16));
    }
    dwA = dW[((size_t)0*BB + b0 + w)*LL + lane];
    dwB = dW[((size_t)0*BB + b0 + w + 8)*LL + lane];
    __syncthreads();
    if (w < 2) {
      f32x4 pc = {0,0,0,0};
      bf16x8 a0 = *(const bf16x8*)(INp + lane*8);
      bf16x8 b0f = *(const bf16x8*)(projWp + (size_t)(0*2 + w)*512 + lane*8);
      pc = MFMA_B16(a0, b0f, pc);
      bf16x8 a1 = *(const bf16x8*)(INp + 512 + lane*8);
      bf16x8 b1f = *(const bf16x8*)(projWp + (size_t)(1*2 + w)*512 + lane*8);
      pc = MFMA_B16(a1, b1f, pc);
      int col = w*16 + (lane & 15);
      float pb = projb[col];
      #pragma unroll
      for (int j = 0; j < 4; ++j) {
        int row = ((lane>>4)<<2) + j;
        out[((size_t)(b0+row)*TT + 0)*DD + col] = pc[j] + pb;
      }
    }
    __syncthreads();
  }

  // ---- SDE scan ----
  for (int t = 0; t < TT-1; ++t) {
    // P1h
    {
      f32x4 acc[4] = {{0,0,0,0},{0,0,0,0},{0,0,0,0},{0,0,0,0}};
      phase4<2>(W1hp, w*4, INp, myslot, lane, acc);
      #pragma unroll
      for (int i = 0; i < 4; ++i) {
        int c = ((w*4 + i)<<4) + (lane & 15);
        float bv = hb1[c];
        #pragma unroll
        for (int j = 0; j < 4; ++j)
          A1[AP_SCAT(((lane>>4)<<2) + j, c)] = (__bf16)softplus_f(acc[i][j] + bv);
      }
    }
    __syncthreads();
    // P2h
    {
      f32x4 acc[4] = {{0,0,0,0},{0,0,0,0},{0,0,0,0},{0,0,0,0}};
      phase4<16>(W2hp, w*4, A1, myslot, lane, acc);
      #pragma unroll
      for (int i = 0; i < 4; ++i) {
        int c = ((w*4 + i)<<4) + (lane & 15);
        float bv = hb2[c];
        #pragma unroll
        for (int j = 0; j < 4; ++j)
          A2[AP_SCAT(((lane>>4)<<2) + j, c)] = (__bf16)softplus_f(acc[i][j] + bv);
      }
    }
    __syncthreads();
    // P3h
    if (w < 4) {
      f32x4 acc = {0,0,0,0};
      phase1<16,4>(W3hp, w, A2, myslot, lane, acc);
      int cl = (w<<4) + (lane & 15);
      float bv = hb3[cl];
      #pragma unroll
      for (int j = 0; j < 4; ++j)
        l3h[(((lane>>4)<<2) + j)*64 + cl] = acc[j] + bv;
    }
    __syncthreads();
    // P1f
    {
      f32x4 acc[4] = {{0,0,0,0},{0,0,0,0},{0,0,0,0},{0,0,0,0}};
      phase4<6>(W1fp, w*4, INp, myslot, lane, acc);
      #pragma unroll
      for (int i = 0; i < 4; ++i) {
        int c = ((w*4 + i)<<4) + (lane & 15);
        float bv = fb1[c];
        #pragma unroll
        for (int j = 0; j < 4; ++j)
          A1[AP_SCAT(((lane>>4)<<2) + j, c)] = (__bf16)softplus_f(acc[i][j] + bv);
      }
    }
    __syncthreads();
    // P2f
    {
      f32x4 acc[4] = {{0,0,0,0},{0,0,0,0},{0,0,0,0},{0,0,0,0}};
      phase4<16>(W2fp, w*4, A1, myslot, lane, acc);
      #pragma unroll
      for (int i = 0; i < 4; ++i) {
        int c = ((w*4 + i)<<4) + (lane & 15);
        float bv = fb2[c];
        #pragma unroll
        for (int j = 0; j < 4; ++j)
          A2[AP_SCAT(((lane>>4)<<2) + j, c)] = (__bf16)softplus_f(acc[i][j] + bv);
      }
    }
    __syncthreads();
    // P3f
    if (w < 4) {
      f32x4 acc = {0,0,0,0};
      phase1<16,4>(W3fp, w, A2, myslot, lane, acc);
      int cl = (w<<4) + (lane & 15);
      float bv = fb3[cl];
      #pragma unroll
      for (int j = 0; j < 4; ++j)
        l3f[(((lane>>4)<<2) + j)*64 + cl] = acc[j] + bv;
    }
    __syncthreads();

    // wait for ctx[t+2] availability before prefetch
    if (t + 2 < TT) {
      if (tid == 0 && known < (uint_t)(t+3)) {
        while (known < (uint_t)(t+3)) {
          uint_t m = 0xffffffffu;
          #pragma unroll
          for (int i = 0; i < 4; ++i) {
            uint_t v = __hip_atomic_load(&prog[rg*4 + i], __ATOMIC_ACQUIRE, __HIP_MEMORY_SCOPE_AGENT);
            m = (v < m) ? v : m;
          }
          known = m;
          if (known < (uint_t)(t+3)) __builtin_amdgcn_s_sleep(4);
        }
      }
      __syncthreads();
    }

    // ---- epilogue ----
    {
      float t0 = ts[t], t1 = ts[t+1];
      float dt = t1 - t0;
      float sqdt = sqrtf(dt);
      float sqA, sqB;
      #pragma unroll
      for (int e = 0; e < 2; ++e) {
        int r = w + e*8, l = lane;
        float zv = e ? zB : zA;
        float gz;
        if (__builtin_expect(fabsf(zv) < 63.9f, 1)) {
          float x = (zv - GZMIN)*GSCALE;
          int jx = (int)x;
          float fr = x - (float)jx;
          const float* gt = &gtab[l*GK + jx];
          float g0v = gt[0], g1v = gt[1];
          gz = g0v + (g1v - g0v)*fr;
        } else {
          float s = 0.f;
          for (int h = 0; h < 512; ++h)
            s += softplus_f(zv*gw1[l*512+h] + gb1[l*512+h]) * gw2[l*512+h];
          gz = sigmoid_f(s + gb2[l]);
        }
        float fzv = l3f[r*64 + l], hzv = l3h[r*64 + l];
        float u = (fzv - hzv)/gz;
        float sq = u*u;
        #pragma unroll
        for (int off = 1; off < 64; off <<= 1) sq += __shfl_xor(sq, off);
        float zn = zv + fzv*dt + gz*sqdt*(e ? dwB : dwA);
        if (e == 0) { sqA = sq; zA = zn; } else { sqB = sq; zB = zn; }
        INp[AP_SCAT(r, l)] = (__bf16)zn;
      }
      dlA += 0.5f*sqA*dt;
      dlB += 0.5f*sqB*dt;
      if (t + 2 < TT) {
        #pragma unroll
        for (int q = 0; q < 2; ++q) {
          int o = tid + q*512;
          int r = o >> 6, u = o & 63;
          uint_t v = __hip_atomic_load(&ctxu[((size_t)(t+2)*BB + b0 + r)*64 + u], __ATOMIC_RELAXED, __HIP_MEMORY_SCOPE_AGENT);
          INp[AP_SCAT(r, 64 + 2*u)]     = bfbits((ushort_t)(v & 0xffffu));
          INp[AP_SCAT(r, 64 + 2*u + 1)] = bfbits((ushort_t)(v >> 16));
        }
      }
      if (t + 1 < TT-1) {
        dwA = dW[((size_t)(t+1)*BB + b0 + w)*LL + lane];
        dwB = dW[((size_t)(t+1)*BB + b0 + w + 8)*LL + lane];
      }
    }
    __syncthreads();

    // proj of z_{t+1}
    if (w < 2) {
      f32x4 pc = {0,0,0,0};
      bf16x8 a0 = *(const bf16x8*)(INp + lane*8);
      bf16x8 b0f = *(const bf16x8*)(projWp + (size_t)(0*2 + w)*512 + lane*8);
      pc = MFMA_B16(a0, b0f, pc);
      bf16x8 a1 = *(const bf16x8*)(INp + 512 + lane*8);
      bf16x8 b1f = *(const bf16x8*)(projWp + (size_t)(1*2 + w)*512 + lane*8);
      pc = MFMA_B16(a1, b1f, pc);
      int col = w*16 + (lane & 15);
      float pb = projb[col];
      #pragma unroll
      for (int j = 0; j < 4; ++j) {
        int row = ((lane>>4)<<2) + j;
        out[((size_t)(b0+row)*TT + (t+1))*DD + col] = pc[j] + pb;
      }
    }
  }

  if (lane == 0) {
    out[(size_t)BB*TT*DD + b0 + w]     = lqA - dlA;
    out[(size_t)BB*TT*DD + b0 + w + 8] = lqB - dlB;
  }
}

extern "C" void kernel_launch(void* const* d_in, const int* in_sizes, int n_in,
                              void* d_out, int out_size, void* d_ws, size_t ws_size,
                              hipStream_t stream)
{
  const float* xs   = (const float*)d_in[0];
  const float* ts   = (const float*)d_in[1];
  const float* eps0 = (const float*)d_in[2];
  const float* dW   = (const float*)d_in[3];
  const float* gruWx= (const float*)d_in[4];
  const float* gruWh= (const float*)d_in[5];
  const float* grub = (const float*)d_in[6];
  const float* encW = (const float*)d_in[7];
  const float* encb = (const float*)d_in[8];
  const float* qzW  = (const float*)d_in[9];
  const float* qzb  = (const float*)d_in[10];
  const float* fW1  = (const float*)d_in[11];
  const float* fb1  = (const float*)d_in[12];
  const float* fW2  = (const float*)d_in[13];
  const float* fb2  = (const float*)d_in[14];
  const float* fW3  = (const float*)d_in[15];
  const float* fb3  = (const float*)d_in[16];
  const float* hW1  = (const float*)d_in[17];
  const float* hb1  = (const float*)d_in[18];
  const float* hW2  = (const float*)d_in[19];
  const float* hb2  = (const float*)d_in[20];
  const float* hW3  = (const float*)d_in[21];
  const float* hb3  = (const float*)d_in[22];
  const float* gw1  = (const float*)d_in[23];
  const float* gb1  = (const float*)d_in[24];
  const float* gw2  = (const float*)d_in[25];
  const float* gb2  = (const float*)d_in[26];
  const float* projW= (const float*)d_in[27];
  const float* projb= (const float*)d_in[28];
  const float* pm   = (const float*)d_in[29];
  const float* pls  = (const float*)d_in[30];
  float* out = (float*)d_out;

  ushort_t* ctxb = (ushort_t*)d_ws;                     // 16,777,216 ushorts
  float* gtab    = (float*)(ctxb + 16777216);           // 262,208 f32
  ushort_t* W1fp = (ushort_t*)(gtab + 262208);
  ushort_t* W1hp = W1fp + 98304;
  ushort_t* W2fp = W1hp + 32768;
  ushort_t* W2hp = W2fp + 262144;
  ushort_t* W3fp = W2hp + 262144;
  ushort_t* W3hp = W3fp + 32768;
  ushort_t* encWb= W3hp + 32768;
  uint_t*   Wgru = (uint_t*)(encWb + 32768);
  ushort_t* Wgn  = (ushort_t*)(Wgru + 73984);
  ushort_t* projWp = Wgn + 73984;
  uint_t* prog   = (uint_t*)(projWp + 2048);            // 128 uints

  hipLaunchKernelGGL(prep_kernel, dim3(3241), dim3(256), 0, stream,
                     fW1, hW1, fW2, hW2, fW3, hW3, gruWx, gruWh, encW, projW,
                     W1fp, W1hp, W2fp, W2hp, W3fp, W3hp, encWb, Wgru, Wgn, projWp);
  hipLaunchKernelGGL(lut_kernel, dim3(1025), dim3(256), 0, stream,
                     gw1, gb1, gw2, gb2, gtab);
  hipMemsetAsync(prog, 0, 128*sizeof(uint_t), stream);
  hipLaunchKernelGGL(mega_kernel, dim3(160), dim3(512), 0, stream,
                     xs, ts, eps0, dW, qzW, qzb, pm, pls,
                     W1fp, W1hp, W2fp, W2hp, W3fp, W3hp,
                     fb1, hb1, fb2, hb2, fb3, hb3,
                     gtab, gw1, gb1, gw2, gb2,
                     Wgru, Wgn, grub, encWb, encb, projWp, projb,
                     ctxb, prog, out);
}